// Round 1
// baseline (1617.804 us; speedup 1.0000x reference)
//
#include <hip/hip_runtime.h>

// VGAE: 8 GCN layers, N=100000 nodes, E=1.6M edges, feature dims 64/128.
// GCN(x,W,b) = P(x)@W + b = P(x@W) + b, P(y) = Adjn@y + dinv^2*y  (linear).
// We propagate on the narrower side and share P(h) between mu0/si0 branches.

#define NODE_F64 64

// ------------------------------------------------------------------ degree
__global__ void count_deg_kernel(const int* __restrict__ dst, int* __restrict__ deg, int E) {
    int i = blockIdx.x * blockDim.x + threadIdx.x;
    if (i < E) atomicAdd(&deg[dst[i]], 1);
}

__global__ void dinv_kernel(const int* __restrict__ deg, float* __restrict__ dinv, int N) {
    int i = blockIdx.x * blockDim.x + threadIdx.x;
    if (i < N) dinv[i] = rsqrtf((float)(deg[i] + 1));
}

// ------------------------------------------------------------------ scan (exclusive prefix sum of deg -> row_start)
__global__ __launch_bounds__(1024) void scan_block_kernel(const int* __restrict__ deg,
                                                          int* __restrict__ row_start,
                                                          int* __restrict__ bsum, int n) {
    __shared__ int s[1024];
    int i = blockIdx.x * 1024 + threadIdx.x;
    int v = (i < n) ? deg[i] : 0;
    s[threadIdx.x] = v;
    __syncthreads();
    for (int off = 1; off < 1024; off <<= 1) {
        int t = (threadIdx.x >= off) ? s[threadIdx.x - off] : 0;
        __syncthreads();
        s[threadIdx.x] += t;
        __syncthreads();
    }
    if (i < n) row_start[i] = s[threadIdx.x] - v;           // exclusive
    if (threadIdx.x == 1023) bsum[blockIdx.x] = s[1023];    // block total
}

__global__ __launch_bounds__(1024) void scan_partials_kernel(int* __restrict__ bsum, int nb) {
    __shared__ int s[1024];
    int v = (threadIdx.x < nb) ? bsum[threadIdx.x] : 0;
    s[threadIdx.x] = v;
    __syncthreads();
    for (int off = 1; off < 1024; off <<= 1) {
        int t = (threadIdx.x >= off) ? s[threadIdx.x - off] : 0;
        __syncthreads();
        s[threadIdx.x] += t;
        __syncthreads();
    }
    if (threadIdx.x < nb) bsum[threadIdx.x] = s[threadIdx.x] - v;  // exclusive
}

__global__ __launch_bounds__(1024) void scan_add_kernel(int* __restrict__ row_start,
                                                        const int* __restrict__ bsum, int N, int E) {
    int i = blockIdx.x * 1024 + threadIdx.x;
    if (i < N) row_start[i] += bsum[blockIdx.x];
    if (i == 0) row_start[N] = E;
}

// ------------------------------------------------------------------ CSR placement
__global__ void place_kernel(const int* __restrict__ src, const int* __restrict__ dst,
                             const int* __restrict__ row_start, int* __restrict__ cnt,
                             int* __restrict__ csr_src, float* __restrict__ csr_w,
                             const float* __restrict__ dinv, int E) {
    int i = blockIdx.x * blockDim.x + threadIdx.x;
    if (i < E) {
        int d = dst[i], s = src[i];
        int pos = row_start[d] + atomicAdd(&cnt[d], 1);
        csr_src[pos] = s;
        csr_w[pos] = dinv[s] * dinv[d];
    }
}

// ------------------------------------------------------------------ propagate: out = Adjn@x + dinv^2*x (+bias, act)
// W = feature width (64 or 128). EPI: 0 none, 1 bias+relu, 2 bias+sigmoid.
// One wave per node; lane = feature (W=64) or feature pair (W=128).
template <int W, int EPI>
__global__ __launch_bounds__(256) void prop_kernel(const float* __restrict__ x, float* __restrict__ out,
                                                   const int* __restrict__ row_start,
                                                   const int* __restrict__ csr_src,
                                                   const float* __restrict__ csr_w,
                                                   const float* __restrict__ dinv,
                                                   const float* __restrict__ bias, int N) {
    int wave = threadIdx.x >> 6, lane = threadIdx.x & 63;
    int node = blockIdx.x * 4 + wave;
    if (node >= N) return;
    int beg = row_start[node], end = row_start[node + 1];
    float di = dinv[node];
    float d2 = di * di;

    if constexpr (W == 64) {
        float acc0 = x[(size_t)node * 64 + lane] * d2;
        float acc1 = 0.f;
        int e = beg;
        for (; e + 1 < end; e += 2) {
            int s0 = csr_src[e], s1 = csr_src[e + 1];
            float w0 = csr_w[e], w1 = csr_w[e + 1];
            acc0 = fmaf(w0, x[(size_t)s0 * 64 + lane], acc0);
            acc1 = fmaf(w1, x[(size_t)s1 * 64 + lane], acc1);
        }
        if (e < end) {
            acc0 = fmaf(csr_w[e], x[(size_t)csr_src[e] * 64 + lane], acc0);
        }
        float v = acc0 + acc1;
        if constexpr (EPI == 1) v = fmaxf(v + bias[lane], 0.f);
        if constexpr (EPI == 2) { v += bias[lane]; v = 1.f / (1.f + __expf(-v)); }
        out[(size_t)node * 64 + lane] = v;
    } else {
        const float2* x2 = (const float2*)x;
        float2 a0 = x2[(size_t)node * 64 + lane];
        a0.x *= d2; a0.y *= d2;
        float2 a1 = make_float2(0.f, 0.f);
        int e = beg;
        for (; e + 1 < end; e += 2) {
            int s0 = csr_src[e], s1 = csr_src[e + 1];
            float w0 = csr_w[e], w1 = csr_w[e + 1];
            float2 v0 = x2[(size_t)s0 * 64 + lane];
            float2 v1 = x2[(size_t)s1 * 64 + lane];
            a0.x = fmaf(w0, v0.x, a0.x); a0.y = fmaf(w0, v0.y, a0.y);
            a1.x = fmaf(w1, v1.x, a1.x); a1.y = fmaf(w1, v1.y, a1.y);
        }
        if (e < end) {
            float w0 = csr_w[e];
            float2 v0 = x2[(size_t)csr_src[e] * 64 + lane];
            a0.x = fmaf(w0, v0.x, a0.x); a0.y = fmaf(w0, v0.y, a0.y);
        }
        float2 v = make_float2(a0.x + a1.x, a0.y + a1.y);
        if constexpr (EPI == 1) {
            v.x = fmaxf(v.x + bias[lane * 2], 0.f);
            v.y = fmaxf(v.y + bias[lane * 2 + 1], 0.f);
        }
        if constexpr (EPI == 2) {
            v.x += bias[lane * 2];     v.x = 1.f / (1.f + __expf(-v.x));
            v.y += bias[lane * 2 + 1]; v.y = 1.f / (1.f + __expf(-v.y));
        }
        ((float2*)out)[(size_t)node * 64 + lane] = v;
    }
}

// ------------------------------------------------------------------ fp32 GEMM: out[N,KO] = X[N,KI]@W[KI,KO] (+bias)(+relu)
// EPI: 0 none (no bias), 1 bias, 2 bias+relu. W staged in LDS; 4x8 register tile per thread.
template <int KI, int KO, int EPI>
__global__ __launch_bounds__(256) void gemm_kernel(const float* __restrict__ X,
                                                   const float* __restrict__ W,
                                                   const float* __restrict__ bias,
                                                   float* __restrict__ out, int N) {
    constexpr int CG = KO / 8;     // col groups (8 cols each)
    constexpr int RG = 256 / CG;   // row groups (4 rows each)
    constexpr int MT = RG * 4;     // rows per block

    __shared__ float sW[KI * KO];
    for (int i = threadIdx.x; i < KI * KO / 4; i += 256)
        ((float4*)sW)[i] = ((const float4*)W)[i];
    __syncthreads();

    int cg = threadIdx.x % CG, rg = threadIdx.x / CG;
    int c0 = cg * 8;
    int r0 = blockIdx.x * MT + rg * 4;

    float acc[4][8] = {};
    for (int k = 0; k < KI; k += 4) {
        float xv[4][4];
        #pragma unroll
        for (int r = 0; r < 4; ++r) {
            int row = r0 + r;
            float4 t = (row < N) ? *(const float4*)&X[(size_t)row * KI + k]
                                 : make_float4(0.f, 0.f, 0.f, 0.f);
            xv[r][0] = t.x; xv[r][1] = t.y; xv[r][2] = t.z; xv[r][3] = t.w;
        }
        #pragma unroll
        for (int kk = 0; kk < 4; ++kk) {
            float4 wa = *(const float4*)&sW[(k + kk) * KO + c0];
            float4 wb = *(const float4*)&sW[(k + kk) * KO + c0 + 4];
            float wv[8] = {wa.x, wa.y, wa.z, wa.w, wb.x, wb.y, wb.z, wb.w};
            #pragma unroll
            for (int r = 0; r < 4; ++r) {
                float xr = xv[r][kk];
                #pragma unroll
                for (int c = 0; c < 8; ++c)
                    acc[r][c] = fmaf(xr, wv[c], acc[r][c]);
            }
        }
    }

    #pragma unroll
    for (int r = 0; r < 4; ++r) {
        int row = r0 + r;
        if (row >= N) continue;
        float o[8];
        #pragma unroll
        for (int c = 0; c < 8; ++c) {
            float v = acc[r][c];
            if constexpr (EPI >= 1) v += bias[c0 + c];
            if constexpr (EPI == 2) v = fmaxf(v, 0.f);
            o[c] = v;
        }
        *(float4*)&out[(size_t)row * KO + c0]     = make_float4(o[0], o[1], o[2], o[3]);
        *(float4*)&out[(size_t)row * KO + c0 + 4] = make_float4(o[4], o[5], o[6], o[7]);
    }
}

// ------------------------------------------------------------------ z = mu + si*eps (float4)
__global__ void z_kernel(const float* __restrict__ mu, const float* __restrict__ si,
                         const float* __restrict__ eps, float* __restrict__ z, int n4) {
    int i = blockIdx.x * blockDim.x + threadIdx.x;
    if (i < n4) {
        float4 m = ((const float4*)mu)[i];
        float4 s = ((const float4*)si)[i];
        float4 e = ((const float4*)eps)[i];
        ((float4*)z)[i] = make_float4(fmaf(s.x, e.x, m.x), fmaf(s.y, e.y, m.y),
                                      fmaf(s.z, e.z, m.z), fmaf(s.w, e.w, m.w));
    }
}

// ------------------------------------------------------------------ launch
extern "C" void kernel_launch(void* const* d_in, const int* in_sizes, int n_in,
                              void* d_out, int out_size, void* d_ws, size_t ws_size,
                              hipStream_t stream) {
    const float* x    = (const float*)d_in[0];
    const float* eps  = (const float*)d_in[1];
    const int*   ei   = (const int*)d_in[2];
    const float* w_in  = (const float*)d_in[3];  const float* b_in  = (const float*)d_in[4];
    const float* w_mu0 = (const float*)d_in[5];  const float* b_mu0 = (const float*)d_in[6];
    const float* w_mu  = (const float*)d_in[7];  const float* b_mu  = (const float*)d_in[8];
    const float* w_si0 = (const float*)d_in[9];  const float* b_si0 = (const float*)d_in[10];
    const float* w_si  = (const float*)d_in[11]; const float* b_si  = (const float*)d_in[12];
    const float* w_z   = (const float*)d_in[13]; const float* b_z   = (const float*)d_in[14];
    const float* w_d0  = (const float*)d_in[15]; const float* b_d0  = (const float*)d_in[16];
    const float* w_out = (const float*)d_in[17]; const float* b_out = (const float*)d_in[18];

    const int N = in_sizes[0] / 64;
    const int E = in_sizes[2] / 2;
    const int* srcI = ei;
    const int* dstI = ei + E;

    // workspace carve (256B aligned)
    auto align = [](size_t v) { return (v + 255) & ~(size_t)255; };
    char* w = (char*)d_ws;
    size_t off = 0;
    int*   deg       = (int*)(w + off); off = align(off + (size_t)N * 4);
    int*   cnt       = (int*)(w + off); off = align(off + (size_t)N * 4);
    int*   row_start = (int*)(w + off); off = align(off + (size_t)(N + 1) * 4);
    int*   bsum      = (int*)(w + off); off = align(off + 1024 * 4);
    float* dinv      = (float*)(w + off); off = align(off + (size_t)N * 4);
    int*   csr_src   = (int*)(w + off); off = align(off + (size_t)E * 4);
    float* csr_w     = (float*)(w + off); off = align(off + (size_t)E * 4);
    float* A         = (float*)(w + off); off = align(off + (size_t)N * 128 * 4);

    // output regions double as scratch (fully overwritten, deterministic)
    float* Cc = (float*)d_out;                 // logits [N*128]; scratch before final write
    float* M  = Cc + (size_t)N * 128;          // mu  [N*64]
    float* S  = M + (size_t)N * 64;            // si  [N*64]
    float* Bm = M;                             // M||S as one [N*128] scratch buffer

    hipMemsetAsync(deg, 0, (size_t)N * 4, stream);
    hipMemsetAsync(cnt, 0, (size_t)N * 4, stream);

    const int TB = 256;
    count_deg_kernel<<<(E + TB - 1) / TB, TB, 0, stream>>>(dstI, deg, E);
    dinv_kernel<<<(N + TB - 1) / TB, TB, 0, stream>>>(deg, dinv, N);
    int nb = (N + 1023) / 1024;
    scan_block_kernel<<<nb, 1024, 0, stream>>>(deg, row_start, bsum, N);
    scan_partials_kernel<<<1, 1024, 0, stream>>>(bsum, nb);
    scan_add_kernel<<<nb, 1024, 0, stream>>>(row_start, bsum, N, E);
    place_kernel<<<(E + TB - 1) / TB, TB, 0, stream>>>(srcI, dstI, row_start, cnt,
                                                       csr_src, csr_w, dinv, E);

    int pgrid = (N + 3) / 4;
    int g128 = (N + 63) / 64;    // GEMM KO=128: 64 rows/block
    int g64  = (N + 127) / 128;  // GEMM KO=64: 128 rows/block

    // 1. px = P(x) -> A [N,64]
    prop_kernel<64, 0><<<pgrid, 256, 0, stream>>>(x, A, row_start, csr_src, csr_w, dinv, nullptr, N);
    // 2. h = relu(px@w_in + b_in) -> Bm [N,128]
    gemm_kernel<64, 128, 2><<<g128, 256, 0, stream>>>(A, w_in, b_in, Bm, N);
    // 3. ph = P(h) -> A [N,128]   (shared by mu0/si0 branches)
    prop_kernel<128, 0><<<pgrid, 256, 0, stream>>>(Bm, A, row_start, csr_src, csr_w, dinv, nullptr, N);
    // 4. mu1 = relu(ph@w_mu0 + b) -> Bm
    gemm_kernel<128, 128, 2><<<g128, 256, 0, stream>>>(A, w_mu0, b_mu0, Bm, N);
    // 5. si1 = relu(ph@w_si0 + b) -> Cc
    gemm_kernel<128, 128, 2><<<g128, 256, 0, stream>>>(A, w_si0, b_si0, Cc, N);
    // 6. tmu = mu1@w_mu -> A [N,64]
    gemm_kernel<128, 64, 0><<<g64, 256, 0, stream>>>(Bm, w_mu, nullptr, A, N);
    // 7. mu = relu(P(tmu) + b_mu) -> M (final output)
    prop_kernel<64, 1><<<pgrid, 256, 0, stream>>>(A, M, row_start, csr_src, csr_w, dinv, b_mu, N);
    // 8. tsi = si1@w_si -> A [N,64]
    gemm_kernel<128, 64, 0><<<g64, 256, 0, stream>>>(Cc, w_si, nullptr, A, N);
    // 9. si = sigmoid(P(tsi) + b_si) -> S (final output)
    prop_kernel<64, 2><<<pgrid, 256, 0, stream>>>(A, S, row_start, csr_src, csr_w, dinv, b_si, N);
    // 10. z = mu + si*eps -> A [N,64]
    z_kernel<<<((N * 16) + TB - 1) / TB, TB, 0, stream>>>(M, S, eps, A, N * 16);
    // 11. pz = P(z) -> Cc [N,64]
    prop_kernel<64, 0><<<pgrid, 256, 0, stream>>>(A, Cc, row_start, csr_src, csr_w, dinv, nullptr, N);
    // 12. r = pz@w_z + b_z -> A [N,128]
    gemm_kernel<64, 128, 1><<<g128, 256, 0, stream>>>(Cc, w_z, b_z, A, N);
    // 13. pr = P(r) -> Cc [N,128]
    prop_kernel<128, 0><<<pgrid, 256, 0, stream>>>(A, Cc, row_start, csr_src, csr_w, dinv, nullptr, N);
    // 14. r2 = relu(pr@w_d0 + b_d0) -> A [N,128]
    gemm_kernel<128, 128, 2><<<g128, 256, 0, stream>>>(Cc, w_d0, b_d0, A, N);
    // 15. pr2 = P(r2) -> Cc [N,128]
    prop_kernel<128, 0><<<pgrid, 256, 0, stream>>>(A, Cc, row_start, csr_src, csr_w, dinv, nullptr, N);
    // 16. logits = pr2@w_out + b_out -> Cc in-place (block reads its own rows before writing; row-sharing threads are wave-lockstep)
    gemm_kernel<128, 128, 1><<<g128, 256, 0, stream>>>(Cc, w_out, b_out, Cc, N);
}

// Round 2
// 1157.695 us; speedup vs baseline: 1.3974x; 1.3974x over previous
//
#include <hip/hip_runtime.h>

// VGAE: 8 GCN layers, N=100000 nodes, E=1.6M edges, feature dims 64/128.
// GCN(x,W,b) = P(x)@W + b, P(y) = Adjn@y + dinv^2*y (linear, commutes with W).
// Propagate on the narrow side; share P(h); decoder layers 1-2 fused via
// P(P(z))@(w_z@w_d0) + c*(b_z@w_d0) + b_d0  (no activation on decoder layer 1).

// ------------------------------------------------------------------ degree
__global__ void count_deg_kernel(const int* __restrict__ dst, int* __restrict__ deg, int E) {
    int i = blockIdx.x * blockDim.x + threadIdx.x;
    if (i < E) atomicAdd(&deg[dst[i]], 1);
}

__global__ void dinv_kernel(const int* __restrict__ deg, float* __restrict__ dinv, int N) {
    int i = blockIdx.x * blockDim.x + threadIdx.x;
    if (i < N) dinv[i] = rsqrtf((float)(deg[i] + 1));
}

// ------------------------------------------------------------------ scan
__global__ __launch_bounds__(1024) void scan_block_kernel(const int* __restrict__ deg,
                                                          int* __restrict__ row_start,
                                                          int* __restrict__ bsum, int n) {
    __shared__ int s[1024];
    int i = blockIdx.x * 1024 + threadIdx.x;
    int v = (i < n) ? deg[i] : 0;
    s[threadIdx.x] = v;
    __syncthreads();
    for (int off = 1; off < 1024; off <<= 1) {
        int t = (threadIdx.x >= off) ? s[threadIdx.x - off] : 0;
        __syncthreads();
        s[threadIdx.x] += t;
        __syncthreads();
    }
    if (i < n) row_start[i] = s[threadIdx.x] - v;
    if (threadIdx.x == 1023) bsum[blockIdx.x] = s[1023];
}

__global__ __launch_bounds__(1024) void scan_partials_kernel(int* __restrict__ bsum, int nb) {
    __shared__ int s[1024];
    int v = (threadIdx.x < nb) ? bsum[threadIdx.x] : 0;
    s[threadIdx.x] = v;
    __syncthreads();
    for (int off = 1; off < 1024; off <<= 1) {
        int t = (threadIdx.x >= off) ? s[threadIdx.x - off] : 0;
        __syncthreads();
        s[threadIdx.x] += t;
        __syncthreads();
    }
    if (threadIdx.x < nb) bsum[threadIdx.x] = s[threadIdx.x] - v;
}

__global__ __launch_bounds__(1024) void scan_add_kernel(int* __restrict__ row_start,
                                                        const int* __restrict__ bsum, int N, int E) {
    int i = blockIdx.x * 1024 + threadIdx.x;
    if (i < N) row_start[i] += bsum[blockIdx.x];
    if (i == 0) row_start[N] = E;
}

// ------------------------------------------------------------------ CSR placement (interleaved {src, w})
__global__ void place_kernel(const int* __restrict__ src, const int* __restrict__ dst,
                             const int* __restrict__ row_start, int* __restrict__ cnt,
                             int2* __restrict__ csr, const float* __restrict__ dinv, int E) {
    int i = blockIdx.x * blockDim.x + threadIdx.x;
    if (i < E) {
        int d = dst[i], s = src[i];
        int pos = row_start[d] + atomicAdd(&cnt[d], 1);
        csr[pos] = make_int2(s, __float_as_int(dinv[s] * dinv[d]));
    }
}

// ------------------------------------------------------------------ prop row-sum c[j] = dinv_j^2 + sum_w
__global__ void rowsum_kernel(const int2* __restrict__ csr, const int* __restrict__ row_start,
                              const float* __restrict__ dinv, float* __restrict__ cvec, int N) {
    int j = blockIdx.x * blockDim.x + threadIdx.x;
    if (j >= N) return;
    float s = dinv[j] * dinv[j];
    int b = row_start[j], e = row_start[j + 1];
    for (int k = b; k < e; ++k) s += __int_as_float(csr[k].y);
    cvec[j] = s;
}

// ------------------------------------------------------------------ Wc = w_z@w_d0 [64,128], bzw = b_z@w_d0 [128]
__global__ void wc_kernel(const float* __restrict__ w_z, const float* __restrict__ b_z,
                          const float* __restrict__ w_d0,
                          float* __restrict__ Wc, float* __restrict__ bzw) {
    int o = blockIdx.x * 256 + threadIdx.x;
    if (o >= 65 * 128) return;
    int i = o >> 7, j = o & 127;
    float s = 0.f;
    for (int k = 0; k < 128; ++k) {
        float a = (i < 64) ? w_z[i * 128 + k] : b_z[k];
        s = fmaf(a, w_d0[k * 128 + j], s);
    }
    if (i < 64) Wc[i * 128 + j] = s;
    else        bzw[j] = s;
}

// ------------------------------------------------------------------ propagate: out = Adjn@x + dinv^2*x (+bias, act)
// One wave per node. Lanes split into EPL=256/W edge slots of L=W/4 lanes
// (float4 per lane) -> multiple edge rows in flight per load instruction.
// EPI: 0 none, 1 bias+relu, 2 bias+sigmoid.
template <int W, int EPI>
__global__ __launch_bounds__(256) void prop_kernel(const float* __restrict__ x, float* __restrict__ out,
                                                   const int* __restrict__ row_start,
                                                   const int2* __restrict__ csr,
                                                   const float* __restrict__ dinv,
                                                   const float* __restrict__ bias, int N) {
    constexpr int L = W / 4;      // lanes per row (float4 units)
    constexpr int EPL = 64 / L;   // edge slots per wave (4 for W=64, 2 for W=128)
    int wave = threadIdx.x >> 6, lane = threadIdx.x & 63;
    int node = blockIdx.x * 4 + wave;
    if (node >= N) return;
    int sub = lane / L, f4 = lane % L;
    int beg = row_start[node], end = row_start[node + 1];
    float di = dinv[node], d2 = di * di;
    const float4* x4 = (const float4*)x;

    float4 acc = make_float4(0.f, 0.f, 0.f, 0.f);
    float4 acc2 = make_float4(0.f, 0.f, 0.f, 0.f);
    for (int base = beg; base < end; base += 2 * EPL) {
        int ea = base + sub, eb = base + sub + EPL;
        bool va = ea < end, vb = eb < end;
        int2 pa = csr[va ? ea : beg];
        int2 pb = csr[vb ? eb : beg];
        float wa = va ? __int_as_float(pa.y) : 0.f;
        float wb = vb ? __int_as_float(pb.y) : 0.f;
        float4 ra = x4[(size_t)pa.x * L + f4];
        float4 rb = x4[(size_t)pb.x * L + f4];
        acc.x = fmaf(wa, ra.x, acc.x);   acc.y = fmaf(wa, ra.y, acc.y);
        acc.z = fmaf(wa, ra.z, acc.z);   acc.w = fmaf(wa, ra.w, acc.w);
        acc2.x = fmaf(wb, rb.x, acc2.x); acc2.y = fmaf(wb, rb.y, acc2.y);
        acc2.z = fmaf(wb, rb.z, acc2.z); acc2.w = fmaf(wb, rb.w, acc2.w);
    }
    acc.x += acc2.x; acc.y += acc2.y; acc.z += acc2.z; acc.w += acc2.w;

    #pragma unroll
    for (int m = L; m < 64; m <<= 1) {
        acc.x += __shfl_xor(acc.x, m);
        acc.y += __shfl_xor(acc.y, m);
        acc.z += __shfl_xor(acc.z, m);
        acc.w += __shfl_xor(acc.w, m);
    }

    float4 sv = x4[(size_t)node * L + f4];
    acc.x = fmaf(d2, sv.x, acc.x); acc.y = fmaf(d2, sv.y, acc.y);
    acc.z = fmaf(d2, sv.z, acc.z); acc.w = fmaf(d2, sv.w, acc.w);

    if constexpr (EPI == 1) {
        float4 b = *(const float4*)&bias[4 * f4];
        acc.x = fmaxf(acc.x + b.x, 0.f); acc.y = fmaxf(acc.y + b.y, 0.f);
        acc.z = fmaxf(acc.z + b.z, 0.f); acc.w = fmaxf(acc.w + b.w, 0.f);
    }
    if constexpr (EPI == 2) {
        float4 b = *(const float4*)&bias[4 * f4];
        acc.x = 1.f / (1.f + __expf(-(acc.x + b.x)));
        acc.y = 1.f / (1.f + __expf(-(acc.y + b.y)));
        acc.z = 1.f / (1.f + __expf(-(acc.z + b.z)));
        acc.w = 1.f / (1.f + __expf(-(acc.w + b.w)));
    }
    if (sub == 0) ((float4*)out)[(size_t)node * L + f4] = acc;
}

// ------------------------------------------------------------------ fp32 GEMM, 64-column tiles (32KB LDS max)
// out[N,KO] = X[N,KI]@W[KI,KO]; blockIdx.y = column tile. NEVER in-place.
// EPI: 0 none, 1 +bias, 2 +bias,relu, 3 +cvec[row]*bias+bias2, relu.
template <int KI, int KO, int EPI>
__global__ __launch_bounds__(256) void gemm_kernel(const float* __restrict__ X,
                                                   const float* __restrict__ Wg,
                                                   const float* __restrict__ bias,
                                                   const float* __restrict__ bias2,
                                                   const float* __restrict__ cvec,
                                                   float* __restrict__ out, int N) {
    constexpr int COLS = 64;
    constexpr int CG = COLS / 8;   // 8 col groups
    constexpr int RG = 256 / CG;   // 32 row groups
    constexpr int MT = RG * 4;     // 128 rows per block

    __shared__ float sW[KI * COLS];
    int colbase = blockIdx.y * COLS;
    for (int i = threadIdx.x; i < KI * COLS / 4; i += 256) {
        int k = i / (COLS / 4), c4 = i % (COLS / 4);
        *(float4*)&sW[k * COLS + c4 * 4] =
            *(const float4*)&Wg[(size_t)k * KO + colbase + c4 * 4];
    }
    __syncthreads();

    int cg = threadIdx.x % CG, rg = threadIdx.x / CG;
    int c0 = cg * 8;
    int r0 = blockIdx.x * MT + rg * 4;

    float acc[4][8] = {};
    for (int k = 0; k < KI; k += 4) {
        float xv[4][4];
        #pragma unroll
        for (int r = 0; r < 4; ++r) {
            int row = r0 + r;
            float4 t = (row < N) ? *(const float4*)&X[(size_t)row * KI + k]
                                 : make_float4(0.f, 0.f, 0.f, 0.f);
            xv[r][0] = t.x; xv[r][1] = t.y; xv[r][2] = t.z; xv[r][3] = t.w;
        }
        #pragma unroll
        for (int kk = 0; kk < 4; ++kk) {
            float4 wa = *(const float4*)&sW[(k + kk) * COLS + c0];
            float4 wb = *(const float4*)&sW[(k + kk) * COLS + c0 + 4];
            float wv[8] = {wa.x, wa.y, wa.z, wa.w, wb.x, wb.y, wb.z, wb.w};
            #pragma unroll
            for (int r = 0; r < 4; ++r) {
                float xr = xv[r][kk];
                #pragma unroll
                for (int c = 0; c < 8; ++c)
                    acc[r][c] = fmaf(xr, wv[c], acc[r][c]);
            }
        }
    }

    #pragma unroll
    for (int r = 0; r < 4; ++r) {
        int row = r0 + r;
        if (row >= N) continue;
        float cv = 0.f;
        if constexpr (EPI == 3) cv = cvec[row];
        float o[8];
        #pragma unroll
        for (int c = 0; c < 8; ++c) {
            float v = acc[r][c];
            int gc = colbase + c0 + c;
            if constexpr (EPI == 1) v += bias[gc];
            if constexpr (EPI == 2) v = fmaxf(v + bias[gc], 0.f);
            if constexpr (EPI == 3) v = fmaxf(v + cv * bias[gc] + bias2[gc], 0.f);
            o[c] = v;
        }
        *(float4*)&out[(size_t)row * KO + colbase + c0]     = make_float4(o[0], o[1], o[2], o[3]);
        *(float4*)&out[(size_t)row * KO + colbase + c0 + 4] = make_float4(o[4], o[5], o[6], o[7]);
    }
}

// ------------------------------------------------------------------ z = mu + si*eps
__global__ void z_kernel(const float* __restrict__ mu, const float* __restrict__ si,
                         const float* __restrict__ eps, float* __restrict__ z, int n4) {
    int i = blockIdx.x * blockDim.x + threadIdx.x;
    if (i < n4) {
        float4 m = ((const float4*)mu)[i];
        float4 s = ((const float4*)si)[i];
        float4 e = ((const float4*)eps)[i];
        ((float4*)z)[i] = make_float4(fmaf(s.x, e.x, m.x), fmaf(s.y, e.y, m.y),
                                      fmaf(s.z, e.z, m.z), fmaf(s.w, e.w, m.w));
    }
}

// ------------------------------------------------------------------ launch
extern "C" void kernel_launch(void* const* d_in, const int* in_sizes, int n_in,
                              void* d_out, int out_size, void* d_ws, size_t ws_size,
                              hipStream_t stream) {
    const float* x    = (const float*)d_in[0];
    const float* eps  = (const float*)d_in[1];
    const int*   ei   = (const int*)d_in[2];
    const float* w_in  = (const float*)d_in[3];  const float* b_in  = (const float*)d_in[4];
    const float* w_mu0 = (const float*)d_in[5];  const float* b_mu0 = (const float*)d_in[6];
    const float* w_mu  = (const float*)d_in[7];  const float* b_mu  = (const float*)d_in[8];
    const float* w_si0 = (const float*)d_in[9];  const float* b_si0 = (const float*)d_in[10];
    const float* w_si  = (const float*)d_in[11]; const float* b_si  = (const float*)d_in[12];
    const float* w_z   = (const float*)d_in[13]; const float* b_z   = (const float*)d_in[14];
    const float* w_d0  = (const float*)d_in[15]; const float* b_d0  = (const float*)d_in[16];
    const float* w_out = (const float*)d_in[17]; const float* b_out = (const float*)d_in[18];

    const int N = in_sizes[0] / 64;
    const int E = in_sizes[2] / 2;
    const int* srcI = ei;
    const int* dstI = ei + E;

    auto align = [](size_t v) { return (v + 255) & ~(size_t)255; };
    char* w = (char*)d_ws;
    size_t off = 0;
    int*   deg       = (int*)(w + off); off = align(off + (size_t)N * 4);      // doubles as cnt
    float* cvec      = (float*)(w + off); off = align(off + (size_t)N * 4);
    int*   row_start = (int*)(w + off); off = align(off + (size_t)(N + 1) * 4);
    int*   bsum      = (int*)(w + off); off = align(off + 1024 * 4);
    float* dinv      = (float*)(w + off); off = align(off + (size_t)N * 4);
    float* Wc        = (float*)(w + off); off = align(off + 64 * 128 * 4);
    float* bzw       = (float*)(w + off); off = align(off + 128 * 4);
    int2*  csr       = (int2*)(w + off); off = align(off + (size_t)E * 8);
    float* A         = (float*)(w + off); off = align(off + (size_t)N * 128 * 4);

    float* Cc = (float*)d_out;            // logits [N*128]
    float* M  = Cc + (size_t)N * 128;     // mu  [N*64]
    float* S  = M + (size_t)N * 64;       // si  [N*64]
    float* Bm = M;                        // M||S as [N*128] scratch (dead before mu/si written)

    const int TB = 256;
    hipMemsetAsync(deg, 0, (size_t)N * 4, stream);
    count_deg_kernel<<<(E + TB - 1) / TB, TB, 0, stream>>>(dstI, deg, E);
    dinv_kernel<<<(N + TB - 1) / TB, TB, 0, stream>>>(deg, dinv, N);
    int nb = (N + 1023) / 1024;
    scan_block_kernel<<<nb, 1024, 0, stream>>>(deg, row_start, bsum, N);
    scan_partials_kernel<<<1, 1024, 0, stream>>>(bsum, nb);
    scan_add_kernel<<<nb, 1024, 0, stream>>>(row_start, bsum, N, E);
    hipMemsetAsync(deg, 0, (size_t)N * 4, stream);   // reuse deg as cnt
    place_kernel<<<(E + TB - 1) / TB, TB, 0, stream>>>(srcI, dstI, row_start, deg, csr, dinv, E);
    rowsum_kernel<<<(N + TB - 1) / TB, TB, 0, stream>>>(csr, row_start, dinv, cvec, N);
    wc_kernel<<<(65 * 128 + 255) / 256, 256, 0, stream>>>(w_z, b_z, w_d0, Wc, bzw);

    int pgrid = (N + 3) / 4;
    dim3 gA((N + 127) / 128, 2);   // KO=128 GEMMs
    dim3 gB((N + 127) / 128, 1);   // KO=64 GEMMs

    // 1. px = P(x) -> A [64]
    prop_kernel<64, 0><<<pgrid, 256, 0, stream>>>(x, A, row_start, csr, dinv, nullptr, N);
    // 2. h = relu(px@w_in + b_in) -> Bm [128]
    gemm_kernel<64, 128, 2><<<gA, 256, 0, stream>>>(A, w_in, b_in, nullptr, nullptr, Bm, N);
    // 3. ph = P(h) -> A [128]  (shared by mu0/si0)
    prop_kernel<128, 0><<<pgrid, 256, 0, stream>>>(Bm, A, row_start, csr, dinv, nullptr, N);
    // 4. mu1 = relu(ph@w_mu0 + b) -> Bm
    gemm_kernel<128, 128, 2><<<gA, 256, 0, stream>>>(A, w_mu0, b_mu0, nullptr, nullptr, Bm, N);
    // 5. si1 = relu(ph@w_si0 + b) -> Cc
    gemm_kernel<128, 128, 2><<<gA, 256, 0, stream>>>(A, w_si0, b_si0, nullptr, nullptr, Cc, N);
    // 6. tmu = mu1@w_mu -> A [64]
    gemm_kernel<128, 64, 0><<<gB, 256, 0, stream>>>(Bm, w_mu, nullptr, nullptr, nullptr, A, N);
    // 7. mu = relu(P(tmu) + b_mu) -> M (final)
    prop_kernel<64, 1><<<pgrid, 256, 0, stream>>>(A, M, row_start, csr, dinv, b_mu, N);
    // 8. tsi = si1@w_si -> A [64]
    gemm_kernel<128, 64, 0><<<gB, 256, 0, stream>>>(Cc, w_si, nullptr, nullptr, nullptr, A, N);
    // 9. si = sigmoid(P(tsi) + b_si) -> S (final)
    prop_kernel<64, 2><<<pgrid, 256, 0, stream>>>(A, S, row_start, csr, dinv, b_si, N);
    // 10. z = mu + si*eps -> A [64]
    z_kernel<<<((N * 16) + TB - 1) / TB, TB, 0, stream>>>(M, S, eps, A, N * 16);
    // 11. pz = P(z) -> Cc [64]
    prop_kernel<64, 0><<<pgrid, 256, 0, stream>>>(A, Cc, row_start, csr, dinv, nullptr, N);
    // 12. ppz = P(pz) -> A [64]
    prop_kernel<64, 0><<<pgrid, 256, 0, stream>>>(Cc, A, row_start, csr, dinv, nullptr, N);
    // 13. r2 = relu(ppz@Wc + cvec*bzw + b_d0) -> Cc [128]  (fused decoder 1+2)
    gemm_kernel<64, 128, 3><<<gA, 256, 0, stream>>>(A, Wc, bzw, b_d0, cvec, Cc, N);
    // 14. pr2 = P(r2) -> A [128]
    prop_kernel<128, 0><<<pgrid, 256, 0, stream>>>(Cc, A, row_start, csr, dinv, nullptr, N);
    // 15. logits = pr2@w_out + b_out -> Cc (final; different buffers, safe with col-tiling)
    gemm_kernel<128, 128, 1><<<gA, 256, 0, stream>>>(A, w_out, b_out, nullptr, nullptr, Cc, N);
}

// Round 3
// 1134.911 us; speedup vs baseline: 1.4255x; 1.0201x over previous
//
#include <hip/hip_runtime.h>

// VGAE: 8 GCN layers, N=100000 nodes, E=1.6M edges, dims 64/128.
// GCN(x,W,b) = P(x)@W + b, P(y) = Adjn@y + dinv^2*y (linear, commutes with W).
// Propagate narrow side; share P(h); decoder layers 1-2 fused:
// r2 = relu(PP(z)@(w_z@w_d0) + cvec*(b_z@w_d0) + b_d0).

// ------------------------------------------------------------------ degree
__global__ void count_deg_kernel(const int* __restrict__ dst, int* __restrict__ deg, int E) {
    int i = blockIdx.x * blockDim.x + threadIdx.x;
    if (i < E) atomicAdd(&deg[dst[i]], 1);
}

__global__ void dinv_kernel(const int* __restrict__ deg, float* __restrict__ dinv, int N) {
    int i = blockIdx.x * blockDim.x + threadIdx.x;
    if (i < N) dinv[i] = rsqrtf((float)(deg[i] + 1));
}

// ------------------------------------------------------------------ scan
__global__ __launch_bounds__(1024) void scan_block_kernel(const int* __restrict__ deg,
                                                          int* __restrict__ row_start,
                                                          int* __restrict__ bsum, int n) {
    __shared__ int s[1024];
    int i = blockIdx.x * 1024 + threadIdx.x;
    int v = (i < n) ? deg[i] : 0;
    s[threadIdx.x] = v;
    __syncthreads();
    for (int off = 1; off < 1024; off <<= 1) {
        int t = (threadIdx.x >= off) ? s[threadIdx.x - off] : 0;
        __syncthreads();
        s[threadIdx.x] += t;
        __syncthreads();
    }
    if (i < n) row_start[i] = s[threadIdx.x] - v;
    if (threadIdx.x == 1023) bsum[blockIdx.x] = s[1023];
}

__global__ __launch_bounds__(1024) void scan_partials_kernel(int* __restrict__ bsum, int nb) {
    __shared__ int s[1024];
    int v = (threadIdx.x < nb) ? bsum[threadIdx.x] : 0;
    s[threadIdx.x] = v;
    __syncthreads();
    for (int off = 1; off < 1024; off <<= 1) {
        int t = (threadIdx.x >= off) ? s[threadIdx.x - off] : 0;
        __syncthreads();
        s[threadIdx.x] += t;
        __syncthreads();
    }
    if (threadIdx.x < nb) bsum[threadIdx.x] = s[threadIdx.x] - v;
}

__global__ __launch_bounds__(1024) void scan_add_kernel(int* __restrict__ row_start,
                                                        const int* __restrict__ bsum, int N, int E) {
    int i = blockIdx.x * 1024 + threadIdx.x;
    if (i < N) row_start[i] += bsum[blockIdx.x];
    if (i == 0) row_start[N] = E;
}

// ------------------------------------------------------------------ CSR placement (interleaved {src, w})
__global__ void place_kernel(const int* __restrict__ src, const int* __restrict__ dst,
                             const int* __restrict__ row_start, int* __restrict__ cnt,
                             int2* __restrict__ csr, const float* __restrict__ dinv, int E) {
    int i = blockIdx.x * blockDim.x + threadIdx.x;
    if (i < E) {
        int d = dst[i], s = src[i];
        int pos = row_start[d] + atomicAdd(&cnt[d], 1);
        csr[pos] = make_int2(s, __float_as_int(dinv[s] * dinv[d]));
    }
}

// ------------------------------------------------------------------ prop row-sum c[j] = dinv_j^2 + sum_w
__global__ void rowsum_kernel(const int2* __restrict__ csr, const int* __restrict__ row_start,
                              const float* __restrict__ dinv, float* __restrict__ cvec, int N) {
    int j = blockIdx.x * blockDim.x + threadIdx.x;
    if (j >= N) return;
    float s = dinv[j] * dinv[j];
    int b = row_start[j], e = row_start[j + 1];
    for (int k = b; k < e; ++k) s += __int_as_float(csr[k].y);
    cvec[j] = s;
}

// ------------------------------------------------------------------ Wc = w_z@w_d0 [64,128], bzw = b_z@w_d0 [128]
__global__ void wc_kernel(const float* __restrict__ w_z, const float* __restrict__ b_z,
                          const float* __restrict__ w_d0,
                          float* __restrict__ Wc, float* __restrict__ bzw) {
    int o = blockIdx.x * 256 + threadIdx.x;
    if (o >= 65 * 128) return;
    int i = o >> 7, j = o & 127;
    float s = 0.f;
    for (int k = 0; k < 128; ++k) {
        float a = (i < 64) ? w_z[i * 128 + k] : b_z[k];
        s = fmaf(a, w_d0[k * 128 + j], s);
    }
    if (i < 64) Wc[i * 128 + j] = s;
    else        bzw[j] = s;
}

// ------------------------------------------------------------------ propagate: out = Adjn@x + dinv^2*x (+bias, act)
// One wave per node; 4 edge slots in flight (16 edges/iter at W=64, 8 at W=128).
// EPI: 0 none, 1 bias+relu, 2 bias+sigmoid (+ fused z = mu + si*eps -> zout).
template <int W, int EPI>
__global__ __launch_bounds__(256) void prop_kernel(const float* __restrict__ x, float* __restrict__ out,
                                                   const int* __restrict__ row_start,
                                                   const int2* __restrict__ csr,
                                                   const float* __restrict__ dinv,
                                                   const float* __restrict__ bias,
                                                   const float* __restrict__ mu,
                                                   const float* __restrict__ eps,
                                                   float* __restrict__ zout, int N) {
    constexpr int L = W / 4;      // lanes per row (float4 units)
    constexpr int EPL = 64 / L;   // edge slots per gather instr
    int wave = threadIdx.x >> 6, lane = threadIdx.x & 63;
    int node = blockIdx.x * 4 + wave;
    if (node >= N) return;
    int sub = lane / L, f4 = lane % L;
    int beg = row_start[node], end = row_start[node + 1];
    float di = dinv[node], d2 = di * di;
    const float4* x4 = (const float4*)x;

    float4 a0 = make_float4(0.f, 0.f, 0.f, 0.f);
    float4 a1 = make_float4(0.f, 0.f, 0.f, 0.f);
    float4 a2 = make_float4(0.f, 0.f, 0.f, 0.f);
    float4 a3 = make_float4(0.f, 0.f, 0.f, 0.f);
    for (int base = beg; base < end; base += 4 * EPL) {
        int e0 = base + 0 * EPL + sub;
        int e1 = base + 1 * EPL + sub;
        int e2 = base + 2 * EPL + sub;
        int e3 = base + 3 * EPL + sub;
        int2 p0 = csr[e0 < end ? e0 : beg];
        int2 p1 = csr[e1 < end ? e1 : beg];
        int2 p2 = csr[e2 < end ? e2 : beg];
        int2 p3 = csr[e3 < end ? e3 : beg];
        float w0 = (e0 < end) ? __int_as_float(p0.y) : 0.f;
        float w1 = (e1 < end) ? __int_as_float(p1.y) : 0.f;
        float w2 = (e2 < end) ? __int_as_float(p2.y) : 0.f;
        float w3 = (e3 < end) ? __int_as_float(p3.y) : 0.f;
        float4 r0 = x4[(size_t)p0.x * L + f4];
        float4 r1 = x4[(size_t)p1.x * L + f4];
        float4 r2 = x4[(size_t)p2.x * L + f4];
        float4 r3 = x4[(size_t)p3.x * L + f4];
        a0.x = fmaf(w0, r0.x, a0.x); a0.y = fmaf(w0, r0.y, a0.y);
        a0.z = fmaf(w0, r0.z, a0.z); a0.w = fmaf(w0, r0.w, a0.w);
        a1.x = fmaf(w1, r1.x, a1.x); a1.y = fmaf(w1, r1.y, a1.y);
        a1.z = fmaf(w1, r1.z, a1.z); a1.w = fmaf(w1, r1.w, a1.w);
        a2.x = fmaf(w2, r2.x, a2.x); a2.y = fmaf(w2, r2.y, a2.y);
        a2.z = fmaf(w2, r2.z, a2.z); a2.w = fmaf(w2, r2.w, a2.w);
        a3.x = fmaf(w3, r3.x, a3.x); a3.y = fmaf(w3, r3.y, a3.y);
        a3.z = fmaf(w3, r3.z, a3.z); a3.w = fmaf(w3, r3.w, a3.w);
    }
    float4 acc;
    acc.x = (a0.x + a1.x) + (a2.x + a3.x);
    acc.y = (a0.y + a1.y) + (a2.y + a3.y);
    acc.z = (a0.z + a1.z) + (a2.z + a3.z);
    acc.w = (a0.w + a1.w) + (a2.w + a3.w);

    #pragma unroll
    for (int m = L; m < 64; m <<= 1) {
        acc.x += __shfl_xor(acc.x, m);
        acc.y += __shfl_xor(acc.y, m);
        acc.z += __shfl_xor(acc.z, m);
        acc.w += __shfl_xor(acc.w, m);
    }

    float4 sv = x4[(size_t)node * L + f4];
    acc.x = fmaf(d2, sv.x, acc.x); acc.y = fmaf(d2, sv.y, acc.y);
    acc.z = fmaf(d2, sv.z, acc.z); acc.w = fmaf(d2, sv.w, acc.w);

    if constexpr (EPI == 1) {
        float4 b = *(const float4*)&bias[4 * f4];
        acc.x = fmaxf(acc.x + b.x, 0.f); acc.y = fmaxf(acc.y + b.y, 0.f);
        acc.z = fmaxf(acc.z + b.z, 0.f); acc.w = fmaxf(acc.w + b.w, 0.f);
    }
    if constexpr (EPI == 2) {
        float4 b = *(const float4*)&bias[4 * f4];
        acc.x = 1.f / (1.f + __expf(-(acc.x + b.x)));
        acc.y = 1.f / (1.f + __expf(-(acc.y + b.y)));
        acc.z = 1.f / (1.f + __expf(-(acc.z + b.z)));
        acc.w = 1.f / (1.f + __expf(-(acc.w + b.w)));
    }
    if (sub == 0) {
        ((float4*)out)[(size_t)node * L + f4] = acc;
        if constexpr (EPI == 2) {
            float4 m4 = ((const float4*)mu)[(size_t)node * L + f4];
            float4 e4 = ((const float4*)eps)[(size_t)node * L + f4];
            float4 z;
            z.x = fmaf(acc.x, e4.x, m4.x); z.y = fmaf(acc.y, e4.y, m4.y);
            z.z = fmaf(acc.z, e4.z, m4.z); z.w = fmaf(acc.w, e4.w, m4.w);
            ((float4*)zout)[(size_t)node * L + f4] = z;
        }
    }
}

// ------------------------------------------------------------------ fp32 GEMM: out[N,KO] = X[N,KI]@W[KI,KO]
// X tile transposed into LDS (Xs[k][row], pad stride) in 64-k chunks; W streamed
// from global (64k-chunk of W = <=32KB, L1-resident per CU). Per-thread RPTx8 tile.
// EPI: 0 none, 1 +bias, 2 +bias,relu, 3 +cvec[row]*bias+bias2, relu.
template <int KI, int KO, int EPI>
__global__ __launch_bounds__(256) void gemm_kernel(const float* __restrict__ X,
                                                   const float* __restrict__ Wg,
                                                   const float* __restrict__ bias,
                                                   const float* __restrict__ bias2,
                                                   const float* __restrict__ cvec,
                                                   float* __restrict__ out, int N) {
    constexpr int MT  = 128;          // rows per block
    constexpr int CG  = KO / 8;       // col groups
    constexpr int RG  = 256 / CG;     // row groups
    constexpr int RPT = MT / RG;      // rows per thread (8 for KO=128, 4 for KO=64)
    constexpr int KB  = 64;           // k chunk
    constexpr int LDX = MT + 4;       // padded LDS row stride (132 floats = 528B, 16B-aligned)

    __shared__ float Xs[KB * LDX];

    int cg = threadIdx.x % CG, rg = threadIdx.x / CG;
    int c0 = cg * 8;
    int r0 = rg * RPT;
    int rowbase = blockIdx.x * MT;

    float acc[RPT][8] = {};

    for (int kc = 0; kc < KI; kc += KB) {
        // stage X[rowbase..rowbase+127][kc..kc+63] transposed -> Xs[k][row]
        #pragma unroll
        for (int t = 0; t < (MT * KB / 4) / 256; ++t) {
            int idx = t * 256 + threadIdx.x;
            int row = idx / (KB / 4);
            int kq  = idx % (KB / 4);
            float4 v = make_float4(0.f, 0.f, 0.f, 0.f);
            int gr = rowbase + row;
            if (gr < N) v = *(const float4*)&X[(size_t)gr * KI + kc + kq * 4];
            Xs[(kq * 4 + 0) * LDX + row] = v.x;
            Xs[(kq * 4 + 1) * LDX + row] = v.y;
            Xs[(kq * 4 + 2) * LDX + row] = v.z;
            Xs[(kq * 4 + 3) * LDX + row] = v.w;
        }
        __syncthreads();

        #pragma unroll 4
        for (int k = 0; k < KB; ++k) {
            int gk = kc + k;
            float4 wa = *(const float4*)&Wg[(size_t)gk * KO + c0];
            float4 wb = *(const float4*)&Wg[(size_t)gk * KO + c0 + 4];
            float wv[8] = {wa.x, wa.y, wa.z, wa.w, wb.x, wb.y, wb.z, wb.w};
            float xr[RPT];
            #pragma unroll
            for (int rq = 0; rq < RPT / 4; ++rq) {
                float4 xv = *(const float4*)&Xs[k * LDX + r0 + rq * 4];
                xr[rq * 4 + 0] = xv.x; xr[rq * 4 + 1] = xv.y;
                xr[rq * 4 + 2] = xv.z; xr[rq * 4 + 3] = xv.w;
            }
            #pragma unroll
            for (int r = 0; r < RPT; ++r) {
                #pragma unroll
                for (int c = 0; c < 8; ++c)
                    acc[r][c] = fmaf(xr[r], wv[c], acc[r][c]);
            }
        }
        __syncthreads();
    }

    #pragma unroll
    for (int r = 0; r < RPT; ++r) {
        int row = rowbase + r0 + r;
        if (row >= N) continue;
        float cv = 0.f;
        if constexpr (EPI == 3) cv = cvec[row];
        float o[8];
        #pragma unroll
        for (int c = 0; c < 8; ++c) {
            float v = acc[r][c];
            int gc = c0 + c;
            if constexpr (EPI == 1) v += bias[gc];
            if constexpr (EPI == 2) v = fmaxf(v + bias[gc], 0.f);
            if constexpr (EPI == 3) v = fmaxf(v + cv * bias[gc] + bias2[gc], 0.f);
            o[c] = v;
        }
        *(float4*)&out[(size_t)row * KO + c0]     = make_float4(o[0], o[1], o[2], o[3]);
        *(float4*)&out[(size_t)row * KO + c0 + 4] = make_float4(o[4], o[5], o[6], o[7]);
    }
}

// ------------------------------------------------------------------ launch
extern "C" void kernel_launch(void* const* d_in, const int* in_sizes, int n_in,
                              void* d_out, int out_size, void* d_ws, size_t ws_size,
                              hipStream_t stream) {
    const float* x    = (const float*)d_in[0];
    const float* eps  = (const float*)d_in[1];
    const int*   ei   = (const int*)d_in[2];
    const float* w_in  = (const float*)d_in[3];  const float* b_in  = (const float*)d_in[4];
    const float* w_mu0 = (const float*)d_in[5];  const float* b_mu0 = (const float*)d_in[6];
    const float* w_mu  = (const float*)d_in[7];  const float* b_mu  = (const float*)d_in[8];
    const float* w_si0 = (const float*)d_in[9];  const float* b_si0 = (const float*)d_in[10];
    const float* w_si  = (const float*)d_in[11]; const float* b_si  = (const float*)d_in[12];
    const float* w_z   = (const float*)d_in[13]; const float* b_z   = (const float*)d_in[14];
    const float* w_d0  = (const float*)d_in[15]; const float* b_d0  = (const float*)d_in[16];
    const float* w_out = (const float*)d_in[17]; const float* b_out = (const float*)d_in[18];

    const int N = in_sizes[0] / 64;
    const int E = in_sizes[2] / 2;
    const int* srcI = ei;
    const int* dstI = ei + E;

    auto align = [](size_t v) { return (v + 255) & ~(size_t)255; };
    char* w = (char*)d_ws;
    size_t off = 0;
    int*   deg       = (int*)(w + off); off = align(off + (size_t)N * 4);      // doubles as cnt
    float* cvec      = (float*)(w + off); off = align(off + (size_t)N * 4);
    int*   row_start = (int*)(w + off); off = align(off + (size_t)(N + 1) * 4);
    int*   bsum      = (int*)(w + off); off = align(off + 1024 * 4);
    float* dinv      = (float*)(w + off); off = align(off + (size_t)N * 4);
    float* Wc        = (float*)(w + off); off = align(off + 64 * 128 * 4);
    float* bzw       = (float*)(w + off); off = align(off + 128 * 4);
    int2*  csr       = (int2*)(w + off); off = align(off + (size_t)E * 8);
    float* A         = (float*)(w + off); off = align(off + (size_t)N * 128 * 4);
    float* A_lo = A;                       // [N,64]
    float* A_hi = A + (size_t)N * 64;      // [N,64]

    float* Cc = (float*)d_out;            // logits [N*128]
    float* M  = Cc + (size_t)N * 128;     // mu  [N*64]
    float* S  = M + (size_t)N * 64;       // si  [N*64]
    float* Bm = M;                        // M||S as [N*128] scratch (dead before mu/si written)

    const int TB = 256;
    hipMemsetAsync(deg, 0, (size_t)N * 4, stream);
    count_deg_kernel<<<(E + TB - 1) / TB, TB, 0, stream>>>(dstI, deg, E);
    dinv_kernel<<<(N + TB - 1) / TB, TB, 0, stream>>>(deg, dinv, N);
    int nb = (N + 1023) / 1024;
    scan_block_kernel<<<nb, 1024, 0, stream>>>(deg, row_start, bsum, N);
    scan_partials_kernel<<<1, 1024, 0, stream>>>(bsum, nb);
    scan_add_kernel<<<nb, 1024, 0, stream>>>(row_start, bsum, N, E);
    hipMemsetAsync(deg, 0, (size_t)N * 4, stream);   // reuse deg as cnt
    place_kernel<<<(E + TB - 1) / TB, TB, 0, stream>>>(srcI, dstI, row_start, deg, csr, dinv, E);
    rowsum_kernel<<<(N + TB - 1) / TB, TB, 0, stream>>>(csr, row_start, dinv, cvec, N);
    wc_kernel<<<(65 * 128 + 255) / 256, 256, 0, stream>>>(w_z, b_z, w_d0, Wc, bzw);

    int pgrid = (N + 3) / 4;
    int ggrid = (N + 127) / 128;

    // 1. px = P(x) -> A [64]
    prop_kernel<64, 0><<<pgrid, 256, 0, stream>>>(x, A, row_start, csr, dinv, nullptr, nullptr, nullptr, nullptr, N);
    // 2. h = relu(px@w_in + b_in) -> Bm [128]
    gemm_kernel<64, 128, 2><<<ggrid, 256, 0, stream>>>(A, w_in, b_in, nullptr, nullptr, Bm, N);
    // 3. ph = P(h) -> A [128]  (shared by mu0/si0)
    prop_kernel<128, 0><<<pgrid, 256, 0, stream>>>(Bm, A, row_start, csr, dinv, nullptr, nullptr, nullptr, nullptr, N);
    // 4. mu1 = relu(ph@w_mu0 + b) -> Bm [128]
    gemm_kernel<128, 128, 2><<<ggrid, 256, 0, stream>>>(A, w_mu0, b_mu0, nullptr, nullptr, Bm, N);
    // 5. si1 = relu(ph@w_si0 + b) -> Cc [128]
    gemm_kernel<128, 128, 2><<<ggrid, 256, 0, stream>>>(A, w_si0, b_si0, nullptr, nullptr, Cc, N);
    // 6. tmu = mu1@w_mu -> A_lo [64]   (ph in A dead after 5; 6 reads Bm)
    gemm_kernel<128, 64, 0><<<ggrid, 256, 0, stream>>>(Bm, w_mu, nullptr, nullptr, nullptr, A_lo, N);
    // 7. mu = relu(P(tmu) + b_mu) -> M (final)
    prop_kernel<64, 1><<<pgrid, 256, 0, stream>>>(A_lo, M, row_start, csr, dinv, b_mu, nullptr, nullptr, nullptr, N);
    // 8. tsi = si1@w_si -> A_hi [64]
    gemm_kernel<128, 64, 0><<<ggrid, 256, 0, stream>>>(Cc, w_si, nullptr, nullptr, nullptr, A_hi, N);
    // 9. si = sigmoid(P(tsi) + b_si) -> S (final); fused z = mu + si*eps -> A_lo (tmu dead)
    prop_kernel<64, 2><<<pgrid, 256, 0, stream>>>(A_hi, S, row_start, csr, dinv, b_si, M, eps, A_lo, N);
    // 10. pz = P(z) -> A_hi (tsi dead)
    prop_kernel<64, 0><<<pgrid, 256, 0, stream>>>(A_lo, A_hi, row_start, csr, dinv, nullptr, nullptr, nullptr, nullptr, N);
    // 11. ppz = P(pz) -> A_lo (z dead)
    prop_kernel<64, 0><<<pgrid, 256, 0, stream>>>(A_hi, A_lo, row_start, csr, dinv, nullptr, nullptr, nullptr, nullptr, N);
    // 12. r2 = relu(ppz@Wc + cvec*bzw + b_d0) -> Cc [128]  (si1 dead; fused decoder 1+2)
    gemm_kernel<64, 128, 3><<<ggrid, 256, 0, stream>>>(A_lo, Wc, bzw, b_d0, cvec, Cc, N);
    // 13. pr2 = P(r2) -> A [128]
    prop_kernel<128, 0><<<pgrid, 256, 0, stream>>>(Cc, A, row_start, csr, dinv, nullptr, nullptr, nullptr, nullptr, N);
    // 14. logits = pr2@w_out + b_out -> Cc (final)
    gemm_kernel<128, 128, 1><<<ggrid, 256, 0, stream>>>(A, w_out, b_out, nullptr, nullptr, Cc, N);
}

// Round 4
// 622.076 us; speedup vs baseline: 2.6007x; 1.8244x over previous
//
#include <hip/hip_runtime.h>

// VGAE: 8 GCN layers, N=100000, E=1.6M, dims 64/128 — bf16 features + MFMA.
// GCN(x,W,b) = P(x)@W + b, P linear => propagate narrow side, share P(h),
// decoder 1-2 fused: r2 = relu(PP(z)@(w_z@w_d0) + cvec*(b_z@w_d0) + b_d0).

typedef short bf16x8 __attribute__((ext_vector_type(8)));
typedef float f32x4 __attribute__((ext_vector_type(4)));

__device__ __forceinline__ ushort f2bf(float f) {           // RNE
    uint x = __float_as_uint(f);
    uint r = x + 0x7FFFu + ((x >> 16) & 1u);
    return (ushort)(r >> 16);
}
__device__ __forceinline__ float bf2f(ushort h) {
    return __uint_as_float(((uint)h) << 16);
}

// ------------------------------------------------------------------ degree
__global__ void count_deg_kernel(const int* __restrict__ dst, int* __restrict__ deg, int E) {
    int i = blockIdx.x * blockDim.x + threadIdx.x;
    if (i < E) atomicAdd(&deg[dst[i]], 1);
}

__global__ void dinv_kernel(const int* __restrict__ deg, float* __restrict__ dinv, int N) {
    int i = blockIdx.x * blockDim.x + threadIdx.x;
    if (i < N) dinv[i] = rsqrtf((float)(deg[i] + 1));
}

// ------------------------------------------------------------------ scan
__global__ __launch_bounds__(1024) void scan_block_kernel(const int* __restrict__ deg,
                                                          int* __restrict__ row_start,
                                                          int* __restrict__ bsum, int n) {
    __shared__ int s[1024];
    int i = blockIdx.x * 1024 + threadIdx.x;
    int v = (i < n) ? deg[i] : 0;
    s[threadIdx.x] = v;
    __syncthreads();
    for (int off = 1; off < 1024; off <<= 1) {
        int t = (threadIdx.x >= off) ? s[threadIdx.x - off] : 0;
        __syncthreads();
        s[threadIdx.x] += t;
        __syncthreads();
    }
    if (i < n) row_start[i] = s[threadIdx.x] - v;
    if (threadIdx.x == 1023) bsum[blockIdx.x] = s[1023];
}

__global__ __launch_bounds__(1024) void scan_partials_kernel(int* __restrict__ bsum, int nb) {
    __shared__ int s[1024];
    int v = (threadIdx.x < nb) ? bsum[threadIdx.x] : 0;
    s[threadIdx.x] = v;
    __syncthreads();
    for (int off = 1; off < 1024; off <<= 1) {
        int t = (threadIdx.x >= off) ? s[threadIdx.x - off] : 0;
        __syncthreads();
        s[threadIdx.x] += t;
        __syncthreads();
    }
    if (threadIdx.x < nb) bsum[threadIdx.x] = s[threadIdx.x] - v;
}

__global__ __launch_bounds__(1024) void scan_add_kernel(int* __restrict__ row_start,
                                                        const int* __restrict__ bsum, int N, int E) {
    int i = blockIdx.x * 1024 + threadIdx.x;
    if (i < N) row_start[i] += bsum[blockIdx.x];
    if (i == 0) row_start[N] = E;
}

// ------------------------------------------------------------------ CSR placement
__global__ void place_kernel(const int* __restrict__ src, const int* __restrict__ dst,
                             const int* __restrict__ row_start, int* __restrict__ cnt,
                             int2* __restrict__ csr, const float* __restrict__ dinv, int E) {
    int i = blockIdx.x * blockDim.x + threadIdx.x;
    if (i < E) {
        int d = dst[i], s = src[i];
        int pos = row_start[d] + atomicAdd(&cnt[d], 1);
        csr[pos] = make_int2(s, __float_as_int(dinv[s] * dinv[d]));
    }
}

// ------------------------------------------------------------------ cvec[j] = dinv_j^2 + sum_w (prop row sum)
__global__ void rowsum_kernel(const int2* __restrict__ csr, const int* __restrict__ row_start,
                              const float* __restrict__ dinv, float* __restrict__ cvec, int N) {
    int j = blockIdx.x * blockDim.x + threadIdx.x;
    if (j >= N) return;
    float s = dinv[j] * dinv[j];
    int b = row_start[j], e = row_start[j + 1];
    for (int k = b; k < e; ++k) s += __int_as_float(csr[k].y);
    cvec[j] = s;
}

// ------------------------------------------------------------------ Wc = w_z@w_d0 [64,128] f32, bzw = b_z@w_d0
__global__ void wc_kernel(const float* __restrict__ w_z, const float* __restrict__ b_z,
                          const float* __restrict__ w_d0,
                          float* __restrict__ Wc, float* __restrict__ bzw) {
    int o = blockIdx.x * 256 + threadIdx.x;
    if (o >= 65 * 128) return;
    int i = o >> 7, j = o & 127;
    float s = 0.f;
    for (int k = 0; k < 128; ++k) {
        float a = (i < 64) ? w_z[i * 128 + k] : b_z[k];
        s = fmaf(a, w_d0[k * 128 + j], s);
    }
    if (i < 64) Wc[i * 128 + j] = s;
    else        bzw[j] = s;
}

// ------------------------------------------------------------------ weight pack: W[KI,KO] f32 -> MFMA B-fragments bf16
// Wp[((c*KB+kb)*64+l)*8+e] = bf16(W[kb*32+(l>>4)*8+e][c*16+(l&15)])
__global__ void pack_kernel(const float* __restrict__ W, ushort* __restrict__ Wp, int KI, int KO) {
    int idx = blockIdx.x * 256 + threadIdx.x;
    if (idx >= KI * KO) return;
    int e = idx & 7, l = (idx >> 3) & 63, t = idx >> 9;
    int KB = KI / 32;
    int c = t / KB, kb = t % KB;
    int k = kb * 32 + (l >> 4) * 8 + e, col = c * 16 + (l & 15);
    Wp[idx] = f2bf(W[(size_t)k * KO + col]);
}

// ------------------------------------------------------------------ f32 -> bf16 (8/thread)
__global__ void cvt8_kernel(const float* __restrict__ in, ushort* __restrict__ out, int n8) {
    int i = blockIdx.x * 256 + threadIdx.x;
    if (i >= n8) return;
    float4 a = ((const float4*)in)[i * 2];
    float4 b = ((const float4*)in)[i * 2 + 1];
    bf16x8 o;
    o[0] = (short)f2bf(a.x); o[1] = (short)f2bf(a.y);
    o[2] = (short)f2bf(a.z); o[3] = (short)f2bf(a.w);
    o[4] = (short)f2bf(b.x); o[5] = (short)f2bf(b.y);
    o[6] = (short)f2bf(b.z); o[7] = (short)f2bf(b.w);
    ((bf16x8*)out)[i] = o;
}

// ------------------------------------------------------------------ bf16 propagate: out = Adjn@x + dinv^2*x (+bias,act)
// One wave per node; L=W/8 lanes per row (16B/lane), EPL=64/L edge slots, 2-deep.
// EPI: 0 none, 1 bias+relu (f32 out), 2 bias+sigmoid (f32 out + fused z->bf16).
// OUT: 0 bf16, 1 f32.
template <int W, int EPI, int OUT>
__global__ __launch_bounds__(256) void bprop_kernel(const ushort* __restrict__ xb, void* __restrict__ outp,
                                                    const int* __restrict__ row_start,
                                                    const int2* __restrict__ csr,
                                                    const float* __restrict__ dinv,
                                                    const float* __restrict__ bias,
                                                    const float* __restrict__ mu,
                                                    const float* __restrict__ eps,
                                                    ushort* __restrict__ zout, int N) {
    constexpr int L = W / 8;
    constexpr int EPL = 64 / L;
    int wave = threadIdx.x >> 6, lane = threadIdx.x & 63;
    int node = blockIdx.x * 4 + wave;
    if (node >= N) return;
    int sub = lane / L, f8 = lane % L;
    int beg = row_start[node], end = row_start[node + 1];
    float d2 = dinv[node]; d2 = d2 * d2;

    float a0[8] = {}, a1[8] = {};
    for (int base = beg; base < end; base += 2 * EPL) {
        int e0 = base + sub, e1 = base + EPL + sub;
        int2 p0 = csr[e0 < end ? e0 : 0];
        int2 p1 = csr[e1 < end ? e1 : 0];
        float w0 = (e0 < end) ? __int_as_float(p0.y) : 0.f;
        float w1 = (e1 < end) ? __int_as_float(p1.y) : 0.f;
        bf16x8 v0 = *(const bf16x8*)(xb + (size_t)p0.x * W + f8 * 8);
        bf16x8 v1 = *(const bf16x8*)(xb + (size_t)p1.x * W + f8 * 8);
        #pragma unroll
        for (int i = 0; i < 8; ++i) a0[i] = fmaf(w0, bf2f((ushort)v0[i]), a0[i]);
        #pragma unroll
        for (int i = 0; i < 8; ++i) a1[i] = fmaf(w1, bf2f((ushort)v1[i]), a1[i]);
    }
    float acc[8];
    #pragma unroll
    for (int i = 0; i < 8; ++i) acc[i] = a0[i] + a1[i];
    #pragma unroll
    for (int m = L; m < 64; m <<= 1) {
        #pragma unroll
        for (int i = 0; i < 8; ++i) acc[i] += __shfl_xor(acc[i], m);
    }
    if (sub != 0) return;

    bf16x8 sv = *(const bf16x8*)(xb + (size_t)node * W + f8 * 8);
    #pragma unroll
    for (int i = 0; i < 8; ++i) acc[i] = fmaf(d2, bf2f((ushort)sv[i]), acc[i]);

    if constexpr (EPI >= 1) {
        float4 b0 = *(const float4*)&bias[f8 * 8];
        float4 b1 = *(const float4*)&bias[f8 * 8 + 4];
        float bv[8] = {b0.x, b0.y, b0.z, b0.w, b1.x, b1.y, b1.z, b1.w};
        if constexpr (EPI == 1) {
            #pragma unroll
            for (int i = 0; i < 8; ++i) acc[i] = fmaxf(acc[i] + bv[i], 0.f);
        } else {
            #pragma unroll
            for (int i = 0; i < 8; ++i) acc[i] = 1.f / (1.f + __expf(-(acc[i] + bv[i])));
        }
    }

    if constexpr (OUT == 0) {
        bf16x8 o;
        #pragma unroll
        for (int i = 0; i < 8; ++i) o[i] = (short)f2bf(acc[i]);
        ((bf16x8*)outp)[(size_t)node * L + f8] = o;
    } else {
        float* of = (float*)outp;
        *(float4*)&of[(size_t)node * W + f8 * 8]     = make_float4(acc[0], acc[1], acc[2], acc[3]);
        *(float4*)&of[(size_t)node * W + f8 * 8 + 4] = make_float4(acc[4], acc[5], acc[6], acc[7]);
    }
    if constexpr (EPI == 2) {
        float4 m0 = *(const float4*)&mu[(size_t)node * W + f8 * 8];
        float4 m1 = *(const float4*)&mu[(size_t)node * W + f8 * 8 + 4];
        float4 e0 = *(const float4*)&eps[(size_t)node * W + f8 * 8];
        float4 e1 = *(const float4*)&eps[(size_t)node * W + f8 * 8 + 4];
        float mv[8] = {m0.x, m0.y, m0.z, m0.w, m1.x, m1.y, m1.z, m1.w};
        float ev[8] = {e0.x, e0.y, e0.z, e0.w, e1.x, e1.y, e1.z, e1.w};
        bf16x8 z;
        #pragma unroll
        for (int i = 0; i < 8; ++i) z[i] = (short)f2bf(fmaf(acc[i], ev[i], mv[i]));
        ((bf16x8*)zout)[(size_t)node * L + f8] = z;
    }
}

// ------------------------------------------------------------------ MFMA GEMM: out[N,KO] = Xb[N,KI]@W + epilogue
// 256 thr = 4 waves; wave w owns rows blockIdx*64 + w*16 (all KO cols).
// A frag: row=l&15, k=(l>>4)*8+e. B from packed Wp. C/D: col=l&15, row=(l>>4)*4+r.
// EPI: 0 none, 1 +bias, 2 +bias,relu, 3 relu(v + cvec[row]*bias + bias2).
// OUT: 0 bf16, 1 f32. Output staged via LDS for coalesced stores.
template <int KI, int KO, int EPI, int OUT>
__global__ __launch_bounds__(256) void mgemm_kernel(const ushort* __restrict__ Xb,
                                                    const bf16x8* __restrict__ Wp,
                                                    const float* __restrict__ bias,
                                                    const float* __restrict__ bias2,
                                                    const float* __restrict__ cvec,
                                                    void* __restrict__ outp, int N) {
    constexpr int KB = KI / 32;
    constexpr int CT = KO / 16;
    constexpr size_t LSB = (OUT == 1) ? (size_t)64 * KO * 4 : (size_t)64 * KO * 2;
    __shared__ __align__(16) char LsRaw[LSB];

    int w = threadIdx.x >> 6, l = threadIdx.x & 63;
    int lr = l & 15, lk = l >> 4;
    int rowbase = blockIdx.x * 64;
    int r0 = rowbase + w * 16;

    int arow = r0 + lr; if (arow > N - 1) arow = N - 1;
    bf16x8 a[KB];
    const ushort* xp = Xb + (size_t)arow * KI + lk * 8;
    #pragma unroll
    for (int kb = 0; kb < KB; ++kb) a[kb] = *(const bf16x8*)(xp + kb * 32);

    float cv[4];
    if constexpr (EPI == 3) {
        #pragma unroll
        for (int r = 0; r < 4; ++r) {
            int rr = r0 + lk * 4 + r;
            cv[r] = cvec[rr < N ? rr : 0];
        }
    }

    #pragma unroll
    for (int c = 0; c < CT; ++c) {
        f32x4 acc = {0.f, 0.f, 0.f, 0.f};
        #pragma unroll
        for (int kb = 0; kb < KB; ++kb)
            acc = __builtin_amdgcn_mfma_f32_16x16x32_bf16(a[kb], Wp[((size_t)c * KB + kb) * 64 + l], acc, 0, 0, 0);
        int col = c * 16 + lr;
        float bv = 0.f, b2v = 0.f;
        if constexpr (EPI >= 1) bv = bias[col];
        if constexpr (EPI == 3) b2v = bias2[col];
        #pragma unroll
        for (int r = 0; r < 4; ++r) {
            float v = acc[r];
            if constexpr (EPI == 1) v += bv;
            if constexpr (EPI == 2) v = fmaxf(v + bv, 0.f);
            if constexpr (EPI == 3) v = fmaxf(v + cv[r] * bv + b2v, 0.f);
            int rl = w * 16 + lk * 4 + r;
            if constexpr (OUT == 0) ((ushort*)LsRaw)[(size_t)rl * KO + col] = f2bf(v);
            else                    ((float*)LsRaw)[(size_t)rl * KO + col] = v;
        }
    }
    __syncthreads();

    if constexpr (OUT == 0) {
        ushort* o = (ushort*)outp;
        constexpr int CH = 64 * KO / 8;
        for (int idx = threadIdx.x; idx < CH; idx += 256) {
            int row = idx / (KO / 8), c8 = idx % (KO / 8);
            if (rowbase + row < N)
                *(bf16x8*)(o + (size_t)(rowbase + row) * KO + c8 * 8) = ((const bf16x8*)LsRaw)[idx];
        }
    } else {
        float* o = (float*)outp;
        constexpr int CH = 64 * KO / 4;
        for (int idx = threadIdx.x; idx < CH; idx += 256) {
            int row = idx / (KO / 4), c4 = idx % (KO / 4);
            if (rowbase + row < N)
                *(float4*)(o + (size_t)(rowbase + row) * KO + c4 * 4) = ((const float4*)LsRaw)[idx];
        }
    }
}

// ------------------------------------------------------------------ launch
extern "C" void kernel_launch(void* const* d_in, const int* in_sizes, int n_in,
                              void* d_out, int out_size, void* d_ws, size_t ws_size,
                              hipStream_t stream) {
    const float* x    = (const float*)d_in[0];
    const float* eps  = (const float*)d_in[1];
    const int*   ei   = (const int*)d_in[2];
    const float* w_in  = (const float*)d_in[3];  const float* b_in  = (const float*)d_in[4];
    const float* w_mu0 = (const float*)d_in[5];  const float* b_mu0 = (const float*)d_in[6];
    const float* w_mu  = (const float*)d_in[7];  const float* b_mu  = (const float*)d_in[8];
    const float* w_si0 = (const float*)d_in[9];  const float* b_si0 = (const float*)d_in[10];
    const float* w_si  = (const float*)d_in[11]; const float* b_si  = (const float*)d_in[12];
    const float* w_z   = (const float*)d_in[13]; const float* b_z   = (const float*)d_in[14];
    const float* w_d0  = (const float*)d_in[15]; const float* b_d0  = (const float*)d_in[16];
    const float* w_out = (const float*)d_in[17]; const float* b_out = (const float*)d_in[18];

    const int N = in_sizes[0] / 64;
    const int E = in_sizes[2] / 2;
    const int* srcI = ei;
    const int* dstI = ei + E;

    auto align = [](size_t v) { return (v + 255) & ~(size_t)255; };
    char* w = (char*)d_ws;
    size_t off = 0;
    int*    deg       = (int*)(w + off);    off = align(off + (size_t)N * 4);   // also cnt
    float*  cvec      = (float*)(w + off);  off = align(off + (size_t)N * 4);
    int*    row_start = (int*)(w + off);    off = align(off + (size_t)(N + 1) * 4);
    int*    bsum      = (int*)(w + off);    off = align(off + 1024 * 4);
    float*  dinv      = (float*)(w + off);  off = align(off + (size_t)N * 4);
    float*  Wc        = (float*)(w + off);  off = align(off + 64 * 128 * 4);
    float*  bzw       = (float*)(w + off);  off = align(off + 128 * 4);
    ushort* P_in      = (ushort*)(w + off); off = align(off + 64 * 128 * 2);
    ushort* P_mu0     = (ushort*)(w + off); off = align(off + 128 * 128 * 2);
    ushort* P_si0     = (ushort*)(w + off); off = align(off + 128 * 128 * 2);
    ushort* P_mu      = (ushort*)(w + off); off = align(off + 128 * 64 * 2);
    ushort* P_si      = (ushort*)(w + off); off = align(off + 128 * 64 * 2);
    ushort* P_wc      = (ushort*)(w + off); off = align(off + 64 * 128 * 2);
    ushort* P_out     = (ushort*)(w + off); off = align(off + 128 * 128 * 2);
    int2*   csr       = (int2*)(w + off);   off = align(off + (size_t)E * 8);
    ushort* xb        = (ushort*)(w + off); off = align(off + (size_t)N * 64 * 2);
    ushort* Ab        = (ushort*)(w + off); off = align(off + (size_t)N * 128 * 2);
    ushort* Ab0 = Ab;                       // [N,64]
    ushort* Ab1 = Ab + (size_t)N * 64;      // [N,64]

    float* Cc = (float*)d_out;              // logits f32 [N,128] (final)
    float* M  = Cc + (size_t)N * 128;       // mu f32 [N,64] (final)
    float* S  = M + (size_t)N * 64;         // si f32 [N,64] (final)
    ushort* Cb_x = (ushort*)Cc;             // bf16 [N,128] scratch (first half of Cc)
    ushort* Cb_y = (ushort*)(Cc + (size_t)N * 64);  // bf16 [N,64.. up to N,128] scratch
    ushort* Db_x = (ushort*)M;              // bf16 [N,128] scratch (= M region exactly)

    const int TB = 256;
    hipMemsetAsync(deg, 0, (size_t)N * 4, stream);
    count_deg_kernel<<<(E + TB - 1) / TB, TB, 0, stream>>>(dstI, deg, E);
    dinv_kernel<<<(N + TB - 1) / TB, TB, 0, stream>>>(deg, dinv, N);
    int nb = (N + 1023) / 1024;
    scan_block_kernel<<<nb, 1024, 0, stream>>>(deg, row_start, bsum, N);
    scan_partials_kernel<<<1, 1024, 0, stream>>>(bsum, nb);
    scan_add_kernel<<<nb, 1024, 0, stream>>>(row_start, bsum, N, E);
    hipMemsetAsync(deg, 0, (size_t)N * 4, stream);
    place_kernel<<<(E + TB - 1) / TB, TB, 0, stream>>>(srcI, dstI, row_start, deg, csr, dinv, E);
    rowsum_kernel<<<(N + TB - 1) / TB, TB, 0, stream>>>(csr, row_start, dinv, cvec, N);
    wc_kernel<<<(65 * 128 + 255) / 256, 256, 0, stream>>>(w_z, b_z, w_d0, Wc, bzw);

    // weight packs + input cvt
    pack_kernel<<<(64 * 128 + 255) / 256, 256, 0, stream>>>(w_in, P_in, 64, 128);
    pack_kernel<<<(128 * 128 + 255) / 256, 256, 0, stream>>>(w_mu0, P_mu0, 128, 128);
    pack_kernel<<<(128 * 128 + 255) / 256, 256, 0, stream>>>(w_si0, P_si0, 128, 128);
    pack_kernel<<<(128 * 64 + 255) / 256, 256, 0, stream>>>(w_mu, P_mu, 128, 64);
    pack_kernel<<<(128 * 64 + 255) / 256, 256, 0, stream>>>(w_si, P_si, 128, 64);
    pack_kernel<<<(64 * 128 + 255) / 256, 256, 0, stream>>>(Wc, P_wc, 64, 128);
    pack_kernel<<<(128 * 128 + 255) / 256, 256, 0, stream>>>(w_out, P_out, 128, 128);
    cvt8_kernel<<<((N * 8) + 255) / 256, 256, 0, stream>>>(x, xb, N * 8);

    int pgrid = (N + 3) / 4;
    int ggrid = (N + 63) / 64;

    // 1. px = P(xb) -> Ab0 [64] bf16
    bprop_kernel<64, 0, 0><<<pgrid, 256, 0, stream>>>(xb, Ab0, row_start, csr, dinv, nullptr, nullptr, nullptr, nullptr, N);
    // 2. h = relu(px@w_in + b_in) -> Cb_x [128] bf16
    mgemm_kernel<64, 128, 2, 0><<<ggrid, 256, 0, stream>>>(Ab0, (const bf16x8*)P_in, b_in, nullptr, nullptr, Cb_x, N);
    // 3. ph = P(h) -> Db_x [128] bf16 (shared by mu0/si0)
    bprop_kernel<128, 0, 0><<<pgrid, 256, 0, stream>>>(Cb_x, Db_x, row_start, csr, dinv, nullptr, nullptr, nullptr, nullptr, N);
    // 4. mu1 = relu(ph@w_mu0 + b) -> Ab [128] bf16 (px dead)
    mgemm_kernel<128, 128, 2, 0><<<ggrid, 256, 0, stream>>>(Db_x, (const bf16x8*)P_mu0, b_mu0, nullptr, nullptr, Ab, N);
    // 5. si1 = relu(ph@w_si0 + b) -> Cb_x [128] bf16 (h dead)
    mgemm_kernel<128, 128, 2, 0><<<ggrid, 256, 0, stream>>>(Db_x, (const bf16x8*)P_si0, b_si0, nullptr, nullptr, Cb_x, N);
    // 6. tmu = mu1@w_mu -> Cb_y [64] bf16
    mgemm_kernel<128, 64, 0, 0><<<ggrid, 256, 0, stream>>>(Ab, (const bf16x8*)P_mu, nullptr, nullptr, nullptr, Cb_y, N);
    // 7. mu = relu(P(tmu) + b_mu) -> M f32 (final; ph dead)
    bprop_kernel<64, 1, 1><<<pgrid, 256, 0, stream>>>(Cb_y, M, row_start, csr, dinv, b_mu, nullptr, nullptr, nullptr, N);
    // 8. tsi = si1@w_si -> Ab0 [64] bf16 (mu1 dead)
    mgemm_kernel<128, 64, 0, 0><<<ggrid, 256, 0, stream>>>(Cb_x, (const bf16x8*)P_si, nullptr, nullptr, nullptr, Ab0, N);
    // 9. si = sigmoid(P(tsi) + b_si) -> S f32 (final); fused z = mu + si*eps -> Ab1 bf16
    bprop_kernel<64, 2, 1><<<pgrid, 256, 0, stream>>>(Ab0, S, row_start, csr, dinv, b_si, M, eps, Ab1, N);
    // 10. pz = P(z) -> Cb_y [64] bf16 (tmu dead)
    bprop_kernel<64, 0, 0><<<pgrid, 256, 0, stream>>>(Ab1, Cb_y, row_start, csr, dinv, nullptr, nullptr, nullptr, nullptr, N);
    // 11. ppz = P(pz) -> Ab0 [64] bf16 (tsi dead)
    bprop_kernel<64, 0, 0><<<pgrid, 256, 0, stream>>>(Cb_y, Ab0, row_start, csr, dinv, nullptr, nullptr, nullptr, nullptr, N);
    // 12. r2 = relu(ppz@Wc + cvec*bzw + b_d0) -> Cb_x [128] bf16 (si1 dead; fused decoder 1+2)
    mgemm_kernel<64, 128, 3, 0><<<ggrid, 256, 0, stream>>>(Ab0, (const bf16x8*)P_wc, bzw, b_d0, cvec, Cb_x, N);
    // 13. pr2 = P(r2) -> Ab [128] bf16 (z/ppz dead -> full Ab free)
    bprop_kernel<128, 0, 0><<<pgrid, 256, 0, stream>>>(Cb_x, Ab, row_start, csr, dinv, nullptr, nullptr, nullptr, nullptr, N);
    // 14. logits = pr2@w_out + b_out -> Cc f32 (final; overwrites Cb_x/Cb_y scratch)
    mgemm_kernel<128, 128, 1, 1><<<ggrid, 256, 0, stream>>>(Ab, (const bf16x8*)P_out, b_out, nullptr, nullptr, Cc, N);
}